// Round 1
// baseline (1034.222 us; speedup 1.0000x reference)
//
#include <hip/hip_runtime.h>
#include <hip/hip_fp16.h>

// binary_dense on MI355X.
// out[b,o] = |gamma| * sum_{l,k} m[l,b,k] * sign(w[16l+c[l,b,k],k,o]) * mask[k,o]
// where c = sign-pattern of (x, x[rm0], x[rm1], x[rm2]) and m = |s0 s1 s2 s3|.
// Only one of the 16 truth-table products is nonzero per (l,b,k); it equals m.
//
// 3 kernels:
//  1) pass_mc:   per (l,b): x row -> LDS, gather shuffles, emit m with c packed
//                into the low 4 mantissa bits (rel err 2^-19).
//  2) main_fma:  grid = 64 k-slices x 8 b-tiles (512 blocks, 2/CU).
//                Round 2 change: occupancy was VGPR-bound at 8 waves/CU
//                (acc[32][4]=128 regs -> >128 unified -> 25% occ, VALUBusy 42%).
//                Now: b-tile 128, wave = 64 lanes x 4 o x 16 b (acc[16][4]=64),
//                __launch_bounds__(512,4) -> 2 blocks/CU = 16 waves/CU so the
//                ds_read_b64 -> 4x v_fma_mix chain is latency-hidden.
//                XCD-chunked swizzle: all 8 bt-blocks of a k-slice land on one
//                XCD so its L2 absorbs the 8x w re-read (512 % 8 == 0, bijective).
//  3) reduce:    sum 64 k-slice partials, apply |gamma| at the end (kept exact).
//
// ws usage: mc 64 MiB + partials 64 MiB = 128 MiB.

#define N_IN   8192
#define N_OUT  256
#define BATCH  1024
#define LEVELS 2

#define KSLICES 64
#define BTILES  8
#define BT      128        // batch rows per block
#define CHUNK_K 8          // real k per lmc chunk
#define ROWP    264        // fp16 row stride (256 + 8 pad -> breaks bank alias)

// ---------------------------------------------------------------- pass 1: (m,c)
__global__ __launch_bounds__(256) void pass_mc(const float* __restrict__ x,
                                               const int* __restrict__ rm0,
                                               const int* __restrict__ rm1,
                                               const int* __restrict__ rm2,
                                               unsigned int* __restrict__ mc) {
  __shared__ float xrow[N_IN];
  const int lb = blockIdx.x;                 // l*BATCH + b
  const size_t base = (size_t)lb * N_IN;
  const float4* xv = (const float4*)(x + base);
  const int t = threadIdx.x;
#pragma unroll
  for (int j = 0; j < 8; ++j) {
    float4 v = xv[t + j * 256];
    *(float4*)&xrow[4 * (t + j * 256)] = v;
  }
  __syncthreads();
#pragma unroll 4
  for (int j = 0; j < 32; ++j) {
    const int k = t + j * 256;
    const int r0 = rm0[k], r1 = rm1[k], r2 = rm2[k];
    const float s0 = xrow[k], s1 = xrow[r0], s2 = xrow[r1], s3 = xrow[r2];
    // |product| is bitwise-exact vs reference's product of magnitudes
    const float m = fabsf(s0 * s1 * s2 * s3);
    const unsigned c = ((s0 < 0.f) ? 8u : 0u) | ((s1 < 0.f) ? 4u : 0u) |
                       ((s2 < 0.f) ? 2u : 0u) | ((s3 < 0.f) ? 1u : 0u);
    mc[base + k] = (__float_as_uint(m) & ~0xFu) | c;   // c in low mantissa bits
  }
}

// ---------------------------------------------------------------- pass 2: FMA
__global__ __launch_bounds__(512, 4) void main_fma(const float* __restrict__ w,
                                                   const float* __restrict__ mask,
                                                   const unsigned int* __restrict__ mc,
                                                   float* __restrict__ part) {
  __shared__ __half lw[4 * 16 * ROWP];                 // 4 k-units x 16 rows (padded)
  __shared__ unsigned int lmc[LEVELS * CHUNK_K * BT];  // (m,c) chunk, [l][kk][b]

  // XCD-chunked bijective swizzle (512 blocks, 8 XCDs -> 64 consecutive work
  // items per XCD; the 8 bt-blocks of each ks are adjacent -> same XCD L2).
  const int bid = blockIdx.x;
  const int wk = (bid & 7) * (KSLICES * BTILES / 8) + (bid >> 3);
  const int ks = wk >> 3;      // k-slice 0..63  (128 real k each)
  const int bt = wk & 7;       // b-tile  0..7   (128 rows each)

  const int t = threadIdx.x;
  const int lane = t & 63;
  const int wid = t >> 6;      // 8 waves
  const int wb = wid * 16;     // wave's b offset in tile

  float acc[16][4];
#pragma unroll
  for (int i = 0; i < 16; ++i) {
    acc[i][0] = 0.f; acc[i][1] = 0.f; acc[i][2] = 0.f; acc[i][3] = 0.f;
  }

  // lw staging role of this thread: one k-unit / row / 32-output segment
  const int s_ku = t >> 7;             // 0..3
  const int s_r  = (t >> 3) & 15;      // 0..15
  const int s_ob = (t & 7) * 32;       // 0..224

  for (int kc = 0; kc < 128 / CHUNK_K; ++kc) {
    const int k0 = ks * 128 + kc * CHUNK_K;
    __syncthreads();                          // lmc (and prev lw) no longer read
    if (t < 256) {
      // stage (m,c): thread -> (l = t>>7, b = t&127), 8 consecutive k
      const int l = t >> 7, b = t & 127;
      const unsigned int* src =
          mc + ((size_t)(l * BATCH + bt * BT + b) * N_IN + k0);
      const uint4 v0 = *(const uint4*)src;
      const uint4 v1 = *(const uint4*)(src + 4);
      unsigned int* dst = &lmc[l * (CHUNK_K * BT) + b];
      dst[0 * BT] = v0.x; dst[1 * BT] = v0.y; dst[2 * BT] = v0.z; dst[3 * BT] = v0.w;
      dst[4 * BT] = v1.x; dst[5 * BT] = v1.y; dst[6 * BT] = v1.z; dst[7 * BT] = v1.w;
    }
    __syncthreads();

    for (int sub = 0; sub < 4; ++sub) {       // 4 k-units per sub, 16 per chunk
      if (sub) __syncthreads();               // prev sub's FMA done before restage
      {
        // stage sign(w)*mask as fp16 (exact for 0/+-1; gamma applied at the end)
        const int u = sub * 4 + s_ku;         // k-unit 0..15: l = u>>3, kk = u&7
        const int l = u >> 3, kk = u & 7;
        const int k = k0 + kk;
        const int row = l * 16 + s_r;
        const float* wsrc = w + ((size_t)(row * N_IN + k) * N_OUT + s_ob);
        const float* msrc = mask + ((size_t)k * N_OUT + s_ob);
        __half hbuf[32];
#pragma unroll
        for (int j = 0; j < 8; ++j) {
          const float4 wv = *(const float4*)(wsrc + j * 4);
          const float4 mv = *(const float4*)(msrc + j * 4);
          hbuf[4 * j + 0] = __float2half((wv.x > 0.f) ? mv.x : ((wv.x < 0.f) ? -mv.x : 0.f));
          hbuf[4 * j + 1] = __float2half((wv.y > 0.f) ? mv.y : ((wv.y < 0.f) ? -mv.y : 0.f));
          hbuf[4 * j + 2] = __float2half((wv.z > 0.f) ? mv.z : ((wv.z < 0.f) ? -mv.z : 0.f));
          hbuf[4 * j + 3] = __float2half((wv.w > 0.f) ? mv.w : ((wv.w < 0.f) ? -mv.w : 0.f));
        }
        __half* dst = &lw[s_ku * (16 * ROWP) + s_r * ROWP + s_ob];
#pragma unroll
        for (int j = 0; j < 4; ++j) *(uint4*)(dst + j * 8) = *(const uint4*)&hbuf[j * 8];
      }
      __syncthreads();

      // select-FMA over 4 k-units x 16 b (per wave) x 4 o (per lane)
#pragma unroll
      for (int ul = 0; ul < 4; ++ul) {
        const int u = sub * 4 + ul;
        const int l = u >> 3, kk = u & 7;
        const unsigned int* mrow = &lmc[l * (CHUNK_K * BT) + kk * BT + wb];
        const __half* wbase = &lw[ul * (16 * ROWP)];
#pragma unroll
        for (int i = 0; i < 16; i += 4) {
          const uint4 q = *(const uint4*)(mrow + i);   // broadcast: 4 b's (m,c)
#define DO_B(UQ, AI)                                                        \
  {                                                                         \
    const unsigned uq = (UQ);                                               \
    const float m = __uint_as_float(uq & ~0xFu);                            \
    union { uint2 u2; __half2 h[2]; } wv_;                                  \
    wv_.u2 = *(const uint2*)(wbase + (uq & 0xFu) * ROWP + lane * 4);        \
    acc[AI][0] += m * __half2float(wv_.h[0].x);                             \
    acc[AI][1] += m * __half2float(wv_.h[0].y);                             \
    acc[AI][2] += m * __half2float(wv_.h[1].x);                             \
    acc[AI][3] += m * __half2float(wv_.h[1].y);                             \
  }
          DO_B(q.x, i + 0)
          DO_B(q.y, i + 1)
          DO_B(q.z, i + 2)
          DO_B(q.w, i + 3)
#undef DO_B
        }
      }
    }
  }

  // write k-slice partial: part[ks][b][o]
  float* dst = part + ((size_t)(ks * BATCH + bt * BT + wb) * N_OUT) + lane * 4;
#pragma unroll
  for (int i = 0; i < 16; ++i) *(float4*)(dst + (size_t)i * N_OUT) = *(const float4*)acc[i];
}

// ---------------------------------------------------------------- pass 3: reduce
__global__ __launch_bounds__(256) void reduce_part(const float* __restrict__ part,
                                                   const float* __restrict__ gamma,
                                                   float* __restrict__ out) {
  const int b = blockIdx.x, o = threadIdx.x;
  const float g = fabsf(gamma[0]);
  const float* p = part + (size_t)b * N_OUT + o;
  float s = 0.f;
#pragma unroll
  for (int ks = 0; ks < KSLICES; ++ks) s += p[(size_t)ks * BATCH * N_OUT];
  out[b * N_OUT + o] = g * s;
}

extern "C" void kernel_launch(void* const* d_in, const int* in_sizes, int n_in,
                              void* d_out, int out_size, void* d_ws, size_t ws_size,
                              hipStream_t stream) {
  const float* x     = (const float*)d_in[0];
  const float* w     = (const float*)d_in[1];
  const float* gamma = (const float*)d_in[2];
  const float* mask  = (const float*)d_in[3];
  const int* rm0     = (const int*)d_in[4];
  const int* rm1     = (const int*)d_in[5];
  const int* rm2     = (const int*)d_in[6];
  float* out = (float*)d_out;

  unsigned int* mc = (unsigned int*)d_ws;                                  // 64 MiB
  float* part = (float*)((char*)d_ws + (size_t)LEVELS * BATCH * N_IN * 4); // 64 MiB
  (void)in_sizes; (void)n_in; (void)out_size; (void)ws_size;

  pass_mc<<<dim3(LEVELS * BATCH), 256, 0, stream>>>(x, rm0, rm1, rm2, mc);
  main_fma<<<dim3(KSLICES * BTILES), 512, 0, stream>>>(w, mask, mc, part);
  reduce_part<<<dim3(BATCH), 256, 0, stream>>>(part, gamma, out);
}

// Round 3
// 914.232 us; speedup vs baseline: 1.1312x; 1.1312x over previous
//
#include <hip/hip_runtime.h>
#include <hip/hip_fp16.h>

// binary_dense on MI355X.
// out[b,o] = |gamma| * sum_{l,k} m[l,b,k] * sign(w[16l+c[l,b,k],k,o]) * mask[k,o]
// where c = sign-pattern of (x, x[rm0], x[rm1], x[rm2]) and m = |s0 s1 s2 s3|.
// Only one of the 16 truth-table products is nonzero per (l,b,k); it equals m.
//
// 3 kernels:
//  1) pass_mc:   per (l,b): x row -> LDS, gather shuffles, emit m with c packed
//                into the low 4 mantissa bits (rel err 2^-19).
//  2) main_fma:  grid = 64 k-slices x 4 b-tiles (256 blocks, 1/CU).
//                Round-1 lesson: occupancy 23->40% left time flat and doubled
//                staging (conflicts 1.26e7->2.52e7) -> NOT wave-issue-bound;
//                bound by per-CU staging phase + LDS pipe. This round:
//                 - BT=256 (halves total convert redundancy/barriers vs BT=128),
//                 - w prefetched 1 sub ahead into 8xfloat4 regs (latency hidden
//                   under prior sub's compute; mask NOT prefetched - reg budget),
//                 - lw double-buffered -> convert(s+1) overlaps compute(s),
//                   1 barrier/sub + 2/chunk (was 10/chunk total).
//                launch_bounds relaxed to (512) only: don't force the allocator
//                at the 256-reg edge (spill risk); occupancy proven non-binding.
//  3) reduce:    sum 64 k-slice partials, apply |gamma| at the end (kept exact).
//
// ws usage: mc 64 MiB + partials 64 MiB = 128 MiB.

#define N_IN   8192
#define N_OUT  256
#define BATCH  1024
#define LEVELS 2

#define KSLICES 64
#define BTILES  4
#define BT      256        // batch rows per block
#define CHUNK_K 8          // real k per lmc chunk
#define ROWP    264        // fp16 row stride (256 + 8 pad -> breaks bank alias)

// ---------------------------------------------------------------- pass 1: (m,c)
__global__ __launch_bounds__(256) void pass_mc(const float* __restrict__ x,
                                               const int* __restrict__ rm0,
                                               const int* __restrict__ rm1,
                                               const int* __restrict__ rm2,
                                               unsigned int* __restrict__ mc) {
  __shared__ float xrow[N_IN];
  const int lb = blockIdx.x;                 // l*BATCH + b
  const size_t base = (size_t)lb * N_IN;
  const float4* xv = (const float4*)(x + base);
  const int t = threadIdx.x;
#pragma unroll
  for (int j = 0; j < 8; ++j) {
    float4 v = xv[t + j * 256];
    *(float4*)&xrow[4 * (t + j * 256)] = v;
  }
  __syncthreads();
#pragma unroll 4
  for (int j = 0; j < 32; ++j) {
    const int k = t + j * 256;
    const int r0 = rm0[k], r1 = rm1[k], r2 = rm2[k];
    const float s0 = xrow[k], s1 = xrow[r0], s2 = xrow[r1], s3 = xrow[r2];
    // |product| is bitwise-exact vs reference's product of magnitudes
    const float m = fabsf(s0 * s1 * s2 * s3);
    const unsigned c = ((s0 < 0.f) ? 8u : 0u) | ((s1 < 0.f) ? 4u : 0u) |
                       ((s2 < 0.f) ? 2u : 0u) | ((s3 < 0.f) ? 1u : 0u);
    mc[base + k] = (__float_as_uint(m) & ~0xFu) | c;   // c in low mantissa bits
  }
}

// ---------------------------------------------------------------- pass 2: FMA
__global__ __launch_bounds__(512) void main_fma(const float* __restrict__ w,
                                                const float* __restrict__ mask,
                                                const unsigned int* __restrict__ mc,
                                                float* __restrict__ part) {
  __shared__ __half lw[2][4 * 16 * ROWP];              // dbuf x 4 k-units x 16 rows
  __shared__ unsigned int lmc[LEVELS * CHUNK_K * BT];  // (m,c) chunk, [l][kk][b]

  // XCD-chunked bijective swizzle (256 blocks, 8 XCDs -> 32 consecutive work
  // items per XCD; the 4 bt-blocks of each ks are adjacent -> same XCD L2).
  const int bid = blockIdx.x;
  const int wk = (bid & 7) * (KSLICES * BTILES / 8) + (bid >> 3);
  const int ks = wk >> 2;      // k-slice 0..63  (128 real k each)
  const int bt = wk & 3;       // b-tile  0..3   (256 rows each)

  const int t = threadIdx.x;
  const int lane = t & 63;
  const int wid = t >> 6;      // 8 waves
  const int wb = wid * 32;     // wave's b offset in tile

  float acc[32][4];
#pragma unroll
  for (int i = 0; i < 32; ++i) {
    acc[i][0] = 0.f; acc[i][1] = 0.f; acc[i][2] = 0.f; acc[i][3] = 0.f;
  }

  // lw staging role of this thread: one k-unit / row / 32-output segment
  const int s_ku = t >> 7;             // 0..3
  const int s_r  = (t >> 3) & 15;      // 0..15
  const int s_ob = (t & 7) * 32;       // 0..224

  // w prefetch (1 sub ahead). 8 x float4 = 32 VGPRs held across one barrier.
  float4 wpre[8];
  auto issue_prefetch = [&](int g) {
    const int sub2 = g & 3;
    const int k0p = ks * 128 + (g >> 2) * CHUNK_K;
    const int u = sub2 * 4 + s_ku;               // k-unit: l = u>>3, kk = u&7
    const int l = u >> 3, kk = u & 7;
    const int kp = k0p + kk;
    const int row = l * 16 + s_r;
    const float* wsrc = w + ((size_t)(row * N_IN + kp) * N_OUT + s_ob);
#pragma unroll
    for (int j = 0; j < 8; ++j) wpre[j] = *(const float4*)(wsrc + j * 4);
  };

  issue_prefetch(0);

  for (int kc = 0; kc < 128 / CHUNK_K; ++kc) {
    const int k0 = ks * 128 + kc * CHUNK_K;
    __syncthreads();                          // prev chunk's compute done (lmc free)
    {
      // stage (m,c): thread -> (l = t>>8, b = t&255), 8 consecutive k
      const int l = t >> 8, b = t & 255;
      const unsigned int* src =
          mc + ((size_t)(l * BATCH + bt * BT + b) * N_IN + k0);
      const uint4 v0 = *(const uint4*)src;
      const uint4 v1 = *(const uint4*)(src + 4);
      unsigned int* dst = &lmc[l * (CHUNK_K * BT) + b];
      dst[0 * BT] = v0.x; dst[1 * BT] = v0.y; dst[2 * BT] = v0.z; dst[3 * BT] = v0.w;
      dst[4 * BT] = v1.x; dst[5 * BT] = v1.y; dst[6 * BT] = v1.z; dst[7 * BT] = v1.w;
    }
    __syncthreads();

    for (int sub = 0; sub < 4; ++sub) {       // 4 k-units per sub, 16 per chunk
      const int g = kc * 4 + sub;             // global sub counter 0..63
      const int buf = g & 1;
      {
        // convert prefetched w (sign(w)*mask as fp16; exact for 0/+-1) into
        // lw[buf]. dbuf: compute(g) reads lw[buf]; the earliest conflicting
        // write is convert(g+2) -> lw[buf], which sits behind barrier(g+1),
        // and every wave's compute(g) precedes its convert(g+1) in program
        // order -> no race.
        const int u = sub * 4 + s_ku;
        const int l = u >> 3, kk = u & 7;
        const int k = k0 + kk;
        const float* msrc = mask + ((size_t)k * N_OUT + s_ob);
        __half hbuf[32];
#pragma unroll
        for (int j = 0; j < 8; ++j) {
          const float4 wv = wpre[j];
          const float4 mv = *(const float4*)(msrc + j * 4);
          hbuf[4 * j + 0] = __float2half((wv.x > 0.f) ? mv.x : ((wv.x < 0.f) ? -mv.x : 0.f));
          hbuf[4 * j + 1] = __float2half((wv.y > 0.f) ? mv.y : ((wv.y < 0.f) ? -mv.y : 0.f));
          hbuf[4 * j + 2] = __float2half((wv.z > 0.f) ? mv.z : ((wv.z < 0.f) ? -mv.z : 0.f));
          hbuf[4 * j + 3] = __float2half((wv.w > 0.f) ? mv.w : ((wv.w < 0.f) ? -mv.w : 0.f));
        }
        __half* dst = &lw[buf][s_ku * (16 * ROWP) + s_r * ROWP + s_ob];
#pragma unroll
        for (int j = 0; j < 4; ++j) *(uint4*)(dst + j * 8) = *(const uint4*)&hbuf[j * 8];
      }
      if (g + 1 < 64) issue_prefetch(g + 1);  // overwrite regs AFTER convert read them
      __syncthreads();                        // lw[buf] writes visible

      // select-FMA over 4 k-units x 32 b (per wave) x 4 o (per lane)
#pragma unroll
      for (int ul = 0; ul < 4; ++ul) {
        const int u = sub * 4 + ul;
        const int l = u >> 3, kk = u & 7;
        const unsigned int* mrow = &lmc[l * (CHUNK_K * BT) + kk * BT + wb];
        const __half* wbase = &lw[buf][ul * (16 * ROWP)];
#pragma unroll
        for (int i = 0; i < 32; i += 4) {
          const uint4 q = *(const uint4*)(mrow + i);   // broadcast: 4 b's (m,c)
#define DO_B(UQ, AI)                                                        \
  {                                                                         \
    const unsigned uq = (UQ);                                               \
    const float m = __uint_as_float(uq & ~0xFu);                            \
    union { uint2 u2; __half2 h[2]; } wv_;                                  \
    wv_.u2 = *(const uint2*)(wbase + (uq & 0xFu) * ROWP + lane * 4);        \
    acc[AI][0] += m * __half2float(wv_.h[0].x);                             \
    acc[AI][1] += m * __half2float(wv_.h[0].y);                             \
    acc[AI][2] += m * __half2float(wv_.h[1].x);                             \
    acc[AI][3] += m * __half2float(wv_.h[1].y);                             \
  }
          DO_B(q.x, i + 0)
          DO_B(q.y, i + 1)
          DO_B(q.z, i + 2)
          DO_B(q.w, i + 3)
#undef DO_B
        }
      }
    }
  }

  // write k-slice partial: part[ks][b][o]
  float* dst = part + ((size_t)(ks * BATCH + bt * BT + wb) * N_OUT) + lane * 4;
#pragma unroll
  for (int i = 0; i < 32; ++i) *(float4*)(dst + (size_t)i * N_OUT) = *(const float4*)acc[i];
}

// ---------------------------------------------------------------- pass 3: reduce
__global__ __launch_bounds__(256) void reduce_part(const float* __restrict__ part,
                                                   const float* __restrict__ gamma,
                                                   float* __restrict__ out) {
  const int b = blockIdx.x, o = threadIdx.x;
  const float g = fabsf(gamma[0]);
  const float* p = part + (size_t)b * N_OUT + o;
  float s = 0.f;
#pragma unroll
  for (int ks = 0; ks < KSLICES; ++ks) s += p[(size_t)ks * BATCH * N_OUT];
  out[b * N_OUT + o] = g * s;
}

extern "C" void kernel_launch(void* const* d_in, const int* in_sizes, int n_in,
                              void* d_out, int out_size, void* d_ws, size_t ws_size,
                              hipStream_t stream) {
  const float* x     = (const float*)d_in[0];
  const float* w     = (const float*)d_in[1];
  const float* gamma = (const float*)d_in[2];
  const float* mask  = (const float*)d_in[3];
  const int* rm0     = (const int*)d_in[4];
  const int* rm1     = (const int*)d_in[5];
  const int* rm2     = (const int*)d_in[6];
  float* out = (float*)d_out;

  unsigned int* mc = (unsigned int*)d_ws;                                  // 64 MiB
  float* part = (float*)((char*)d_ws + (size_t)LEVELS * BATCH * N_IN * 4); // 64 MiB
  (void)in_sizes; (void)n_in; (void)out_size; (void)ws_size;

  pass_mc<<<dim3(LEVELS * BATCH), 256, 0, stream>>>(x, rm0, rm1, rm2, mc);
  main_fma<<<dim3(KSLICES * BTILES), 512, 0, stream>>>(w, mask, mc, part);
  reduce_part<<<dim3(BATCH), 256, 0, stream>>>(part, gamma, out);
}